// Round 8
// baseline (2168.655 us; speedup 1.0000x reference)
//
#include <hip/hip_runtime.h>
#include <cstdint>

#define N_A 40000
#define N_P 100000
#define N_T 20000
#define D 128
#define OUT_DIM 64
#define E_AP 500000
#define E_PT 800000

typedef __attribute__((ext_vector_type(8))) short bf16x8;
typedef __attribute__((ext_vector_type(4))) float f32x4;

static inline int ceil_div(int a, int b){ return (a + b - 1) / b; }

__device__ inline unsigned short f2bf(float f){           // round-nearest-even
  uint32_t u = __builtin_bit_cast(uint32_t, f);
  uint32_t r = (u + 0x7FFFu + ((u >> 16) & 1u)) >> 16;
  return (unsigned short)r;
}
__device__ inline float bf2f(unsigned short h){
  uint32_t u = ((uint32_t)h) << 16;
  return __builtin_bit_cast(float, u);
}
// truncation split: hi = trunc16(v), lo = rn(v - hi); packed into a uint
__device__ inline uint32_t tsplit_pack(float v){
  uint32_t u = __builtin_bit_cast(uint32_t, v);
  uint32_t h = u >> 16;
  float rem = v - __builtin_bit_cast(float, u & 0xFFFF0000u);
  uint32_t l = f2bf(rem);
  return h | (l << 16);          // low16 = hi-plane, high16 = lo-plane
}

// ---------------- CSR build ----------------
__global__ void hist_kernel(const int* __restrict__ dst, int E, int* __restrict__ cnt){
  int i = blockIdx.x * blockDim.x + threadIdx.x;
  if (i < E) atomicAdd(&cnt[dst[i]], 1);
}

__global__ void block_sums_kernel(const int* __restrict__ cnt, int n, int* __restrict__ bsums){
  __shared__ int red[256];
  int b = blockIdx.x, t = threadIdx.x;
  int base = b * 1024;
  int s = 0;
  for (int i = t; i < 1024; i += 256){ int idx = base + i; if (idx < n) s += cnt[idx]; }
  red[t] = s; __syncthreads();
  for (int off = 128; off > 0; off >>= 1){ if (t < off) red[t] += red[t + off]; __syncthreads(); }
  if (t == 0) bsums[b] = red[0];
}

__global__ void scan_bsums_kernel(int* bsums, int nb){
  __shared__ int sh[128];
  int t = threadIdx.x;
  int v = (t < nb) ? bsums[t] : 0;
  sh[t] = v; __syncthreads();
  int inc = v;
  for (int off = 1; off < 128; off <<= 1){
    int x = (t >= off) ? sh[t - off] : 0; __syncthreads();
    inc += x; sh[t] = inc; __syncthreads();
  }
  if (t < nb) bsums[t] = inc - v;   // exclusive
}

__global__ void scan_final_kernel(const int* __restrict__ cnt, int n, const int* __restrict__ bsums,
                                  int* __restrict__ rowptr, int E){
  __shared__ int sh[256];
  int b = blockIdx.x, t = threadIdx.x;
  int base = b * 1024 + t * 4;
  int v[4]; int s = 0;
  #pragma unroll
  for (int j = 0; j < 4; j++){ int idx = base + j; v[j] = (idx < n) ? cnt[idx] : 0; s += v[j]; }
  sh[t] = s; __syncthreads();
  int inc = s;
  for (int off = 1; off < 256; off <<= 1){
    int x = (t >= off) ? sh[t - off] : 0; __syncthreads();
    inc += x; sh[t] = inc; __syncthreads();
  }
  int run = inc - s + bsums[b];
  #pragma unroll
  for (int j = 0; j < 4; j++){ int idx = base + j; if (idx < n) rowptr[idx] = run; run += v[j]; }
  if (b == 0 && t == 0) rowptr[n] = E;
}

__global__ void cursor_inv_kernel(const int* __restrict__ rowptr, const int* __restrict__ cnt,
                                  int n, int* __restrict__ cursor, float* __restrict__ inv){
  int i = blockIdx.x * blockDim.x + threadIdx.x;
  if (i < n){
    cursor[i] = rowptr[i];
    int c = cnt[i];
    inv[i] = 1.0f / (float)(c > 0 ? c : 1);
  }
}

__global__ void fill_kernel(const int* __restrict__ src, const int* __restrict__ dst, int E,
                            int* __restrict__ cursor, int* __restrict__ eidx){
  int i = blockIdx.x * blockDim.x + threadIdx.x;
  if (i < E){
    int d = dst[i];
    int pos = atomicAdd(&cursor[d], 1);
    eidx[pos] = src[i];
  }
}

// ---------------- weight/bias combine for the paper relation pair ----------------
__global__ void combine_wr_kernel(const float* __restrict__ Wr, float* __restrict__ wrc){
  int i = blockIdx.x * blockDim.x + threadIdx.x;
  if (i < 6 * D * D){
    int sl = i >> 14; int off = i & (D * D - 1);
    wrc[i] = Wr[(size_t)(sl * 4 + 0) * D * D + off] + Wr[(size_t)(sl * 4 + 3) * D * D + off];
  }
}

__global__ void combine_bias_kernel(const float* __restrict__ bl, float* __restrict__ bcomb){
  int i = blockIdx.x * blockDim.x + threadIdx.x;
  if (i < 6 * D){
    int sl = i >> 7; int off = i & (D - 1);
    bcomb[i] = bl[(size_t)(sl * 4 + 0) * D + off] + bl[(size_t)(sl * 4 + 3) * D + off];
  }
}

// ---------------- weight split+pack into MFMA b-frag layout ----------------
// ids 0-23 = W_l, 24-47 = W_r, 48-53 = wrc, 54 = lin_model_W (N=64)
// dst[((kc*(N/16)+cf)*64 + lane)*8 + i] = bf16(W[(kc*32+(lane>>4)*8+i)*N + cf*16+(lane&15)])
__global__ __launch_bounds__(256)
void pack_weights_kernel(const float* __restrict__ W_l, const float* __restrict__ W_r,
                         const float* __restrict__ wrc, const float* __restrict__ linW,
                         unsigned short* __restrict__ packs){
  int id = blockIdx.x;
  const float* src; int N = 128;
  if (id < 24)      src = W_l + (size_t)id * 16384;
  else if (id < 48) src = W_r + (size_t)(id - 24) * 16384;
  else if (id < 54) src = wrc + (size_t)(id - 48) * 16384;
  else            { src = linW; N = 64; }
  unsigned short* dhi = packs + (size_t)id * 32768;
  unsigned short* dlo = dhi + 16384;
  int ncf = N / 16;
  int slots = 4 * ncf * 64;
  for (int s = threadIdx.x; s < slots; s += 256){
    int frag = s >> 6, l = s & 63;
    int kc = frag / ncf, cf = frag - kc * ncf;
    int kb = kc * 32 + ((l >> 4) * 8);
    int col = cf * 16 + (l & 15);
    bf16x8 hv, lv;
    #pragma unroll
    for (int i = 0; i < 8; ++i){
      float f = src[(size_t)(kb + i) * N + col];
      unsigned short h = f2bf(f);
      hv[i] = (short)h;
      lv[i] = (short)f2bf(f - bf2f(h));
    }
    *(bf16x8*)(dhi + (size_t)s * 8) = hv;
    *(bf16x8*)(dlo + (size_t)s * 8) = lv;
  }
}

// ---------------- row accumulate helpers for aggregation ----------------
__device__ inline void addrow_f32(const float* __restrict__ base, int s, int c, float* acc){
  const float4* p = (const float4*)(base + (size_t)s * D + c * 8);
  float4 a = p[0], b = p[1];
  acc[0] += a.x; acc[1] += a.y; acc[2] += a.z; acc[3] += a.w;
  acc[4] += b.x; acc[5] += b.y; acc[6] += b.z; acc[7] += b.w;
}
__device__ inline void addrow_bf(const unsigned short* __restrict__ H,
                                 const unsigned short* __restrict__ L, int s, int c, float* acc){
  bf16x8 h = *(const bf16x8*)(H + (size_t)s * D + c * 8);
  bf16x8 l = *(const bf16x8*)(L + (size_t)s * D + c * 8);
  #pragma unroll
  for (int i = 0; i < 8; ++i)
    acc[i] += bf2f((unsigned short)h[i]) + bf2f((unsigned short)l[i]);
}

// ---------------- mean aggregation -> split planes ----------------
// 16 lanes per dst row (4 rows per wave). SRCF32: source is fp32 [n,D]; else split planes.
template<bool SRCF32>
__global__ __launch_bounds__(256)
void agg_mean_kernel(const int* __restrict__ rowptr, const int* __restrict__ eidx,
                     const float* __restrict__ inv,
                     const void* __restrict__ srcHv, const void* __restrict__ srcLv,
                     unsigned short* __restrict__ dstH, unsigned short* __restrict__ dstL,
                     int ndst){
  int g = (blockIdx.x * blockDim.x + threadIdx.x) >> 4;
  if (g >= ndst) return;
  int c = threadIdx.x & 15;
  int beg = rowptr[g], end = rowptr[g + 1];
  float acc[8];
  #pragma unroll
  for (int i = 0; i < 8; ++i) acc[i] = 0.f;
  const float* F = (const float*)srcHv;
  const unsigned short* H = (const unsigned short*)srcHv;
  const unsigned short* L = (const unsigned short*)srcLv;
  int e = beg;
  for (; e + 4 <= end; e += 4){
    int s0 = eidx[e], s1 = eidx[e + 1], s2 = eidx[e + 2], s3 = eidx[e + 3];
    if (SRCF32){
      addrow_f32(F, s0, c, acc); addrow_f32(F, s1, c, acc);
      addrow_f32(F, s2, c, acc); addrow_f32(F, s3, c, acc);
    } else {
      addrow_bf(H, L, s0, c, acc); addrow_bf(H, L, s1, c, acc);
      addrow_bf(H, L, s2, c, acc); addrow_bf(H, L, s3, c, acc);
    }
  }
  for (; e < end; ++e){
    int s0 = eidx[e];
    if (SRCF32) addrow_f32(F, s0, c, acc);
    else        addrow_bf(H, L, s0, c, acc);
  }
  float iv = inv[g];
  bf16x8 hv, lv;
  #pragma unroll
  for (int i = 0; i < 8; ++i){
    uint32_t pk = tsplit_pack(acc[i] * iv);
    hv[i] = (short)(pk & 0xFFFF);
    lv[i] = (short)(pk >> 16);
  }
  *(bf16x8*)(dstH + (size_t)g * D + c * 8) = hv;
  *(bf16x8*)(dstL + (size_t)g * D + c * 8) = lv;
}

// ---------------- MFMA split-bf16 GEMM, LDS-free ----------------
// out = epi( sum_i A_i[M,128] @ W_i[128, NCFT*16] + bias ).
// A input i: split planes (aH,aL) OR fp32 (bit i of F32MASK set; aH = float*, in-loop split).
// product = Ahi*Bhi + Alo*Bhi + Ahi*Blo. 256 threads / 4 waves.
// WC = NCFT/4 waves along N, WR = 4/WC along M; wave tile = MF*16 rows x 64 cols.
template<int NIN, int F32MASK, int NCFT, int MF, bool RELU, bool DIV, bool OUT32>
__global__ __launch_bounds__(256)
void gemm_mfma(const void* __restrict__ aH0, const unsigned short* __restrict__ aL0,
               const unsigned short* __restrict__ wH0, const unsigned short* __restrict__ wL0,
               const void* __restrict__ aH1, const unsigned short* __restrict__ aL1,
               const unsigned short* __restrict__ wH1, const unsigned short* __restrict__ wL1,
               const void* __restrict__ aH2, const unsigned short* __restrict__ aL2,
               const unsigned short* __restrict__ wH2, const unsigned short* __restrict__ wL2,
               const float* __restrict__ bias, const float* __restrict__ tdiv,
               void* __restrict__ outp, size_t out_lo_off, int nrows){
  constexpr int WC = NCFT / 4;
  constexpr int WR = 4 / WC;
  const int tid    = threadIdx.x;
  const int w      = tid >> 6;
  const int l      = tid & 63;
  const int lane15 = l & 15;
  const int colg   = l >> 4;
  const int wr     = w / WC, wc = w % WC;
  const int rbase  = blockIdx.x * (WR * MF * 16) + wr * (MF * 16);

  f32x4 acc[MF][4];
  #pragma unroll
  for (int m = 0; m < MF; ++m)
    #pragma unroll
    for (int cf = 0; cf < 4; ++cf) acc[m][cf] = (f32x4){0.f, 0.f, 0.f, 0.f};

  const void* aHs[3]           = {aH0, aH1, aH2};
  const unsigned short* aLs[3] = {aL0, aL1, aL2};
  const unsigned short* wHs[3] = {wH0, wH1, wH2};
  const unsigned short* wLs[3] = {wL0, wL1, wL2};

  #pragma unroll
  for (int inp = 0; inp < NIN; ++inp){
    const bf16x8* WH = (const bf16x8*)wHs[inp];
    const bf16x8* WL = (const bf16x8*)wLs[inp];
    #pragma unroll
    for (int kc = 0; kc < 4; ++kc){
      bf16x8 bh[4], bl[4];
      #pragma unroll
      for (int cf = 0; cf < 4; ++cf){
        int idx = (kc * NCFT + wc * 4 + cf) * 64 + l;
        bh[cf] = WH[idx];
        bl[cf] = WL[idx];
      }
      bf16x8 ah[MF], al[MF];
      #pragma unroll
      for (int m = 0; m < MF; ++m){
        int gr = rbase + m * 16 + lane15; if (gr >= nrows) gr = nrows - 1;
        if ((F32MASK >> inp) & 1){
          const float* Af = (const float*)aHs[inp];
          const float4* p = (const float4*)(Af + (size_t)gr * 128 + kc * 32 + colg * 8);
          float4 v0 = p[0], v1 = p[1];
          float fs[8] = {v0.x, v0.y, v0.z, v0.w, v1.x, v1.y, v1.z, v1.w};
          #pragma unroll
          for (int i = 0; i < 8; ++i){
            uint32_t pk = tsplit_pack(fs[i]);
            ah[m][i] = (short)(pk & 0xFFFF);
            al[m][i] = (short)(pk >> 16);
          }
        } else {
          const unsigned short* AH = (const unsigned short*)aHs[inp];
          const unsigned short* AL = aLs[inp];
          size_t idx = (size_t)gr * 128 + kc * 32 + colg * 8;
          ah[m] = *(const bf16x8*)(AH + idx);
          al[m] = *(const bf16x8*)(AL + idx);
        }
      }
      #pragma unroll
      for (int cf = 0; cf < 4; ++cf){
        #pragma unroll
        for (int m = 0; m < MF; ++m){
          acc[m][cf] = __builtin_amdgcn_mfma_f32_16x16x32_bf16(ah[m], bh[cf], acc[m][cf], 0, 0, 0);
          acc[m][cf] = __builtin_amdgcn_mfma_f32_16x16x32_bf16(al[m], bh[cf], acc[m][cf], 0, 0, 0);
          acc[m][cf] = __builtin_amdgcn_mfma_f32_16x16x32_bf16(ah[m], bl[cf], acc[m][cf], 0, 0, 0);
        }
      }
    }
  }

  // epilogue: D row = colg*4 + i, col = (wc*4+cf)*16 + lane15
  #pragma unroll
  for (int cf = 0; cf < 4; ++cf){
    int col = (wc * 4 + cf) * 16 + lane15;
    float bv = bias[col];
    #pragma unroll
    for (int m = 0; m < MF; ++m){
      #pragma unroll
      for (int i = 0; i < 4; ++i){
        int gr = rbase + m * 16 + colg * 4 + i;
        if (gr < nrows){
          float v = acc[m][cf][i] + bv;
          if (RELU) v = fmaxf(v, 0.f);
          if (DIV)  v = v / tdiv[gr];
          size_t oi = (size_t)gr * (NCFT * 16) + col;
          if (OUT32){
            ((float*)outp)[oi] = v;
          } else {
            uint32_t pk = tsplit_pack(v);
            ((unsigned short*)outp)[oi] = (unsigned short)(pk & 0xFFFF);
            ((unsigned short*)outp)[out_lo_off + oi] = (unsigned short)(pk >> 16);
          }
        }
      }
    }
  }
}

// ---------------- temperature fold ----------------
__global__ void wtc_kernel(const float* __restrict__ Wt, const float* __restrict__ bt,
                           const float* __restrict__ W2, const float* __restrict__ b2,
                           float* __restrict__ wtc){
  int k = threadIdx.x;
  if (k < 128){
    float s = 0.f;
    #pragma unroll 4
    for (int j = 0; j < 64; ++j) s += Wt[k * 64 + j] * W2[j];
    wtc[k] = s;
  }
  if (k == 0){
    float s = 0.f;
    for (int j = 0; j < 64; ++j) s += bt[j] * W2[j];
    wtc[128] = s + b2[0];
  }
}

__global__ __launch_bounds__(256)
void temp_kernel(const unsigned short* __restrict__ taH, const unsigned short* __restrict__ taL,
                 const float* __restrict__ wtc, float* __restrict__ temp, int n){
  int w = (blockIdx.x * blockDim.x + threadIdx.x) >> 6;
  if (w >= n) return;
  int l = threadIdx.x & 63;
  ushort2 h = *(const ushort2*)(taH + (size_t)w * D + 2 * l);
  ushort2 lo = *(const ushort2*)(taL + (size_t)w * D + 2 * l);
  float2 c = ((const float2*)wtc)[l];
  float s = (bf2f(h.x) + bf2f(lo.x)) * c.x + (bf2f(h.y) + bf2f(lo.y)) * c.y;
  #pragma unroll
  for (int off = 32; off > 0; off >>= 1) s += __shfl_xor(s, off);
  if (l == 0) temp[w] = s + wtc[128];
}

// ---------------- host ----------------
struct Split { unsigned short* h; unsigned short* l; };

extern "C" void kernel_launch(void* const* d_in, const int* in_sizes, int n_in,
                              void* d_out, int out_size, void* d_ws, size_t ws_size,
                              hipStream_t stream){
  const float* x_author    = (const float*)d_in[0];
  const float* x_paper     = (const float*)d_in[1];
  const float* x_term      = (const float*)d_in[2];
  const float* W_l         = (const float*)d_in[3];
  const float* b_l         = (const float*)d_in[4];
  const float* W_r         = (const float*)d_in[5];
  const float* lin_model_W = (const float*)d_in[6];
  const float* lin_model_b = (const float*)d_in[7];
  const float* lin_temp_W  = (const float*)d_in[8];
  const float* lin_temp_b  = (const float*)d_in[9];
  const float* lin2_W      = (const float*)d_in[10];
  const float* lin2_b      = (const float*)d_in[11];
  const int* src_ap = (const int*)d_in[12];
  const int* dst_ap = (const int*)d_in[13];
  const int* src_pa = (const int*)d_in[14];
  const int* dst_pa = (const int*)d_in[15];
  const int* src_pt = (const int*)d_in[16];
  const int* dst_pt = (const int*)d_in[17];
  const int* src_tp = (const int*)d_in[18];
  const int* dst_tp = (const int*)d_in[19];

  // ---- workspace carve (~316 MB, matches round-4 footprint that fit) ----
  char* wp = (char*)d_ws;
  auto alloc = [&](size_t bytes)->void*{
    void* r = (void*)wp; wp += (bytes + 255) & ~(size_t)255; return r;
  };
  auto mkSplit = [&](int n)->Split{
    unsigned short* p = (unsigned short*)alloc((size_t)n * D * 4);
    return {p, p + (size_t)n * D};
  };
  int*   rowptr_ap = (int*)alloc((N_P + 1) * 4);
  int*   cnt_ap    = (int*)alloc(N_P * 4);
  int*   cur_ap    = (int*)alloc(N_P * 4);
  int*   eidx_ap   = (int*)alloc((size_t)E_AP * 4);
  float* inv_ap    = (float*)alloc(N_P * 4);
  int*   rowptr_pa = (int*)alloc((N_A + 1) * 4);
  int*   cnt_pa    = (int*)alloc(N_A * 4);
  int*   cur_pa    = (int*)alloc(N_A * 4);
  int*   eidx_pa   = (int*)alloc((size_t)E_AP * 4);
  float* inv_pa    = (float*)alloc(N_A * 4);
  int*   rowptr_pt = (int*)alloc((N_T + 1) * 4);
  int*   cnt_pt    = (int*)alloc(N_T * 4);
  int*   cur_pt    = (int*)alloc(N_T * 4);
  int*   eidx_pt   = (int*)alloc((size_t)E_PT * 4);
  float* inv_pt    = (float*)alloc(N_T * 4);
  int*   rowptr_tp = (int*)alloc((N_P + 1) * 4);
  int*   cnt_tp    = (int*)alloc(N_P * 4);
  int*   cur_tp    = (int*)alloc(N_P * 4);
  int*   eidx_tp   = (int*)alloc((size_t)E_PT * 4);
  float* inv_tp    = (float*)alloc(N_P * 4);
  int*   bsums     = (int*)alloc(1024 * 4);
  unsigned short* packs = (unsigned short*)alloc((size_t)55 * 32768 * 2);
  float* wrc   = (float*)alloc((size_t)6 * D * D * 4);
  float* bcomb = (float*)alloc((size_t)6 * D * 4);
  float* wtc   = (float*)alloc(129 * 4);
  float* temp  = (float*)alloc((size_t)N_A * 4);
  // shared aggregation buffers (split planes)
  Split gA = mkSplit(N_A), gP1 = mkSplit(N_P), gP2 = mkSplit(N_P), gT = mkSplit(N_T);
  // activation banks (split planes)
  Split A1 = mkSplit(N_A), P1 = mkSplit(N_P), T1 = mkSplit(N_T);
  Split A2 = mkSplit(N_A), P2 = mkSplit(N_P), T2 = mkSplit(N_T);
  // aliases: stack-2 bank dead after its layer-1; reuse for ma/mp/mt
  Split A0 = A2, P0 = P2, T0 = T2;
  Split TA = P2;   // temperature-stack author out (written after P0 dead)

  // ---- build CSR for the 4 relations ----
  auto build = [&](const int* src, const int* dst, int E, int n,
                   int* rowptr, int* cnt, int* cursor, int* eidx, float* inv){
    (void)hipMemsetAsync(cnt, 0, (size_t)n * 4, stream);
    hist_kernel<<<ceil_div(E, 256), 256, 0, stream>>>(dst, E, cnt);
    int nb = ceil_div(n, 1024);
    block_sums_kernel<<<nb, 256, 0, stream>>>(cnt, n, bsums);
    scan_bsums_kernel<<<1, 128, 0, stream>>>(bsums, nb);
    scan_final_kernel<<<nb, 256, 0, stream>>>(cnt, n, bsums, rowptr, E);
    cursor_inv_kernel<<<ceil_div(n, 256), 256, 0, stream>>>(rowptr, cnt, n, cursor, inv);
    fill_kernel<<<ceil_div(E, 256), 256, 0, stream>>>(src, dst, E, cursor, eidx);
  };
  build(src_ap, dst_ap, E_AP, N_P, rowptr_ap, cnt_ap, cur_ap, eidx_ap, inv_ap);
  build(src_pa, dst_pa, E_AP, N_A, rowptr_pa, cnt_pa, cur_pa, eidx_pa, inv_pa);
  build(src_pt, dst_pt, E_PT, N_T, rowptr_pt, cnt_pt, cur_pt, eidx_pt, inv_pt);
  build(src_tp, dst_tp, E_PT, N_P, rowptr_tp, cnt_tp, cur_tp, eidx_tp, inv_tp);

  combine_wr_kernel<<<ceil_div(6 * D * D, 256), 256, 0, stream>>>(W_r, wrc);
  combine_bias_kernel<<<ceil_div(6 * D, 256), 256, 0, stream>>>(b_l, bcomb);
  pack_weights_kernel<<<55, 256, 0, stream>>>(W_l, W_r, wrc, lin_model_W, packs);
  wtc_kernel<<<1, 128, 0, stream>>>(lin_temp_W, lin_temp_b, lin2_W, lin2_b, wtc);

  auto HI = [&](int id){ return packs + (size_t)id * 32768; };
  auto LO = [&](int id){ return packs + (size_t)id * 32768 + 16384; };
  auto IDL = [&](int s, int l, int r){ return (s * 2 + l) * 4 + r; };
  auto IDR = [&](int s, int l, int r){ return 24 + (s * 2 + l) * 4 + r; };
  auto IDC = [&](int s, int l){ return 48 + s * 2 + l; };
  auto Bl  = [&](int s, int l, int r){ return b_l + (size_t)((s * 2 + l) * 4 + r) * D; };
  auto BC  = [&](int s, int l){ return bcomb + (size_t)(s * 2 + l) * D; };

  auto aggB = [&](const int* rowptr, const int* eidx, const float* inv,
                  Split src, Split dst, int ndst){
    agg_mean_kernel<false><<<ceil_div(ndst, 16), 256, 0, stream>>>(
        rowptr, eidx, inv, (const void*)src.h, (const void*)src.l, dst.h, dst.l, ndst);
  };
  auto aggF = [&](const int* rowptr, const int* eidx, const float* inv,
                  const float* src, Split dst, int ndst){
    agg_mean_kernel<true><<<ceil_div(ndst, 16), 256, 0, stream>>>(
        rowptr, eidx, inv, (const void*)src, nullptr, dst.h, dst.l, ndst);
  };

  // aggregate all 4 relations (split-plane source)
  auto agg_all = [&](Split ia, Split ip, Split it){
    aggB(rowptr_ap, eidx_ap, inv_ap, ia, gP1, N_P);
    aggB(rowptr_tp, eidx_tp, inv_tp, it, gP2, N_P);
    aggB(rowptr_pa, eidx_pa, inv_pa, ip, gA, N_A);
    aggB(rowptr_pt, eidx_pt, inv_pt, ip, gT, N_T);
  };

  // layer-0 GEMMs (lin_r input is raw fp32, in-loop split for that input only)
  auto gemms_l0 = [&](int s, Split oa, Split op, Split ot){
    gemm_mfma<3, 4, 8, 4, true, false, false><<<ceil_div(N_P, 128), 256, 0, stream>>>(
        (const void*)gP1.h, gP1.l, HI(IDL(s, 0, 0)), LO(IDL(s, 0, 0)),
        (const void*)gP2.h, gP2.l, HI(IDL(s, 0, 3)), LO(IDL(s, 0, 3)),
        (const void*)x_paper, nullptr, HI(IDC(s, 0)), LO(IDC(s, 0)),
        BC(s, 0), nullptr, (void*)op.h, (size_t)(op.l - op.h), N_P);
    gemm_mfma<2, 2, 8, 2, true, false, false><<<ceil_div(N_A, 64), 256, 0, stream>>>(
        (const void*)gA.h, gA.l, HI(IDL(s, 0, 1)), LO(IDL(s, 0, 1)),
        (const void*)x_author, nullptr, HI(IDR(s, 0, 1)), LO(IDR(s, 0, 1)),
        nullptr, nullptr, nullptr, nullptr,
        Bl(s, 0, 1), nullptr, (void*)oa.h, (size_t)(oa.l - oa.h), N_A);
    gemm_mfma<2, 2, 8, 2, true, false, false><<<ceil_div(N_T, 64), 256, 0, stream>>>(
        (const void*)gT.h, gT.l, HI(IDL(s, 0, 2)), LO(IDL(s, 0, 2)),
        (const void*)x_term, nullptr, HI(IDR(s, 0, 2)), LO(IDR(s, 0, 2)),
        nullptr, nullptr, nullptr, nullptr,
        Bl(s, 0, 2), nullptr, (void*)ot.h, (size_t)(ot.l - ot.h), N_T);
  };

  // interior-layer GEMMs; outputs split (oa/op/ot) or fp32 (oa32/...)
  auto gemms = [&](Split ia, Split ip, Split it, int s, int l,
                   Split* oa, Split* op, Split* ot,
                   float* oa32, float* op32, float* ot32){
    if (op || op32){
      if (op) gemm_mfma<3, 0, 8, 4, true, false, false><<<ceil_div(N_P, 128), 256, 0, stream>>>(
          (const void*)gP1.h, gP1.l, HI(IDL(s, l, 0)), LO(IDL(s, l, 0)),
          (const void*)gP2.h, gP2.l, HI(IDL(s, l, 3)), LO(IDL(s, l, 3)),
          (const void*)ip.h,  ip.l,  HI(IDC(s, l)),    LO(IDC(s, l)),
          BC(s, l), nullptr, (void*)op->h, (size_t)(op->l - op->h), N_P);
      else gemm_mfma<3, 0, 8, 4, true, false, true><<<ceil_div(N_P, 128), 256, 0, stream>>>(
          (const void*)gP1.h, gP1.l, HI(IDL(s, l, 0)), LO(IDL(s, l, 0)),
          (const void*)gP2.h, gP2.l, HI(IDL(s, l, 3)), LO(IDL(s, l, 3)),
          (const void*)ip.h,  ip.l,  HI(IDC(s, l)),    LO(IDC(s, l)),
          BC(s, l), nullptr, (void*)op32, 0, N_P);
    }
    if (oa || oa32){
      if (oa) gemm_mfma<2, 0, 8, 2, true, false, false><<<ceil_div(N_A, 64), 256, 0, stream>>>(
          (const void*)gA.h, gA.l, HI(IDL(s, l, 1)), LO(IDL(s, l, 1)),
          (const void*)ia.h, ia.l, HI(IDR(s, l, 1)), LO(IDR(s, l, 1)),
          nullptr, nullptr, nullptr, nullptr,
          Bl(s, l, 1), nullptr, (void*)oa->h, (size_t)(oa->l - oa->h), N_A);
      else gemm_mfma<2, 0, 8, 2, true, false, true><<<ceil_div(N_A, 64), 256, 0, stream>>>(
          (const void*)gA.h, gA.l, HI(IDL(s, l, 1)), LO(IDL(s, l, 1)),
          (const void*)ia.h, ia.l, HI(IDR(s, l, 1)), LO(IDR(s, l, 1)),
          nullptr, nullptr, nullptr, nullptr,
          Bl(s, l, 1), nullptr, (void*)oa32, 0, N_A);
    }
    if (ot || ot32){
      if (ot) gemm_mfma<2, 0, 8, 2, true, false, false><<<ceil_div(N_T, 64), 256, 0, stream>>>(
          (const void*)gT.h, gT.l, HI(IDL(s, l, 2)), LO(IDL(s, l, 2)),
          (const void*)it.h, it.l, HI(IDR(s, l, 2)), LO(IDR(s, l, 2)),
          nullptr, nullptr, nullptr, nullptr,
          Bl(s, l, 2), nullptr, (void*)ot->h, (size_t)(ot->l - ot->h), N_T);
      else gemm_mfma<2, 0, 8, 2, true, false, true><<<ceil_div(N_T, 64), 256, 0, stream>>>(
          (const void*)gT.h, gT.l, HI(IDL(s, l, 2)), LO(IDL(s, l, 2)),
          (const void*)it.h, it.l, HI(IDR(s, l, 2)), LO(IDR(s, l, 2)),
          nullptr, nullptr, nullptr, nullptr,
          Bl(s, l, 2), nullptr, (void*)ot32, 0, N_T);
    }
  };

  float* out_logits = (float*)d_out;
  float* out_oa = out_logits + (size_t)N_A * OUT_DIM;
  float* out_op = out_oa + (size_t)N_A * D;
  float* out_ot = out_op + (size_t)N_P * D;

  // layer-0 aggregations of raw fp32 features -- shared by stack 0 and stack 2
  aggF(rowptr_ap, eidx_ap, inv_ap, x_author, gP1, N_P);
  aggF(rowptr_tp, eidx_tp, inv_tp, x_term,   gP2, N_P);
  aggF(rowptr_pa, eidx_pa, inv_pa, x_paper,  gA,  N_A);
  aggF(rowptr_pt, eidx_pt, inv_pt, x_paper,  gT,  N_T);
  gemms_l0(0, A1, P1, T1);   // stack 0 layer 0
  gemms_l0(2, A2, P2, T2);   // stack 2 layer 0 (same aggs!)
  // stack 2 layer 1 -> final conv outputs (fp32 into d_out)
  agg_all(A2, P2, T2);
  gemms(A2, P2, T2, 2, 1, nullptr, nullptr, nullptr, out_oa, out_op, out_ot);
  // stack 0 layer 1 -> ma, mp, mt (A0/P0/T0 alias dead A2/P2/T2)
  agg_all(A1, P1, T1);
  gemms(A1, P1, T1, 0, 1, &A0, &P0, &T0, nullptr, nullptr, nullptr);
  // stack 1 layer 0 on ma,mp,mt -> bank 1
  agg_all(A0, P0, T0);
  gemms(A0, P0, T0, 1, 0, &A1, &P1, &T1, nullptr, nullptr, nullptr);
  // stack 1 layer 1: only the author output needed (TA aliases dead P0)
  aggB(rowptr_pa, eidx_pa, inv_pa, P1, gA, N_A);
  gemm_mfma<2, 0, 8, 2, true, false, false><<<ceil_div(N_A, 64), 256, 0, stream>>>(
      (const void*)gA.h, gA.l, HI(IDL(1, 1, 1)), LO(IDL(1, 1, 1)),
      (const void*)A1.h, A1.l, HI(IDR(1, 1, 1)), LO(IDR(1, 1, 1)),
      nullptr, nullptr, nullptr, nullptr,
      Bl(1, 1, 1), nullptr, (void*)TA.h, (size_t)(TA.l - TA.h), N_A);
  // temperature scalar per author, then logits GEMM with divide epilogue
  temp_kernel<<<ceil_div(N_A, 4), 256, 0, stream>>>(TA.h, TA.l, wtc, temp, N_A);
  gemm_mfma<1, 0, 4, 2, false, true, true><<<ceil_div(N_A, 128), 256, 0, stream>>>(
      (const void*)A0.h, A0.l, HI(54), LO(54),
      nullptr, nullptr, nullptr, nullptr,
      nullptr, nullptr, nullptr, nullptr,
      lin_model_b, temp, (void*)out_logits, 0, N_A);
}